// Round 13
// baseline (137.729 us; speedup 1.0000x reference)
//
#include <hip/hip_runtime.h>

// Problem shape (fixed; established r6/r7/r10/r11/r12):
//   d_in[0]: (1024, 256) int32  ids in [0, 30522)
//   d_in[1]: (1024, 256) f32    weights uniform [0,1)
//   d_out:   (1024, 30522) f32  -- harness reads float32. Value = bf16
//            (RN-even) of the per-(row,id) weight max, 0 baseline.
//            r11/r12 passed bit-exact (absmax 0.0).
#define BATCH     1024
#define SEQ       256
#define VOCAB     30522
#define ROWS_PER_BLOCK 2
#define THREADS   512
// Two rows = 61044 f32 = 244176 B = 15261 uint4 exactly; block base byte
// offset = blk * 244176, which is 16-divisible -> pure uint4 zero stores.
#define BLK_U4    15261

// Fused zero+scatter: each block owns 2 consecutive rows.
// Phase 1: zero the 2 rows with 16B/lane uint4 stores (coalesced, aligned).
// Phase 2 (after block-local sync): scatter the block's 512 tokens with a
// hardware u32 atomicMax on the f32 bit pattern. Nonneg IEEE f32 bit
// patterns are order-isomorphic to values and RN-even bf16 rounding is
// monotone on nonneg inputs, so round-then-max == reference's
// max-then-round, bit-exact. Targets lie inside the block's own rows, so
// the zero->scatter dependency is block-local (no device-wide barrier).
extern "C" __global__ __launch_bounds__(THREADS)
void TargetEncoder_532575944857_kernel(const int* __restrict__ ids,
                                       const float* __restrict__ ws,
                                       unsigned int* __restrict__ out) {
    const int blk = blockIdx.x;
    const int t   = threadIdx.x;

    // ---- Phase 0: load this block's 512 tokens (coalesced) ----
    const int tok = blk * (ROWS_PER_BLOCK * SEQ) + t;
    const int   id = ids[tok];
    const float w  = ws[tok];

    // ---- Phase 1: zero the block's 2 rows (uint4, 16B aligned) ----
    uint4* zbase = (uint4*)(out + (long long)blk * (ROWS_PER_BLOCK * VOCAB));
    const uint4 z = make_uint4(0u, 0u, 0u, 0u);
    #pragma unroll 4
    for (int i = t; i < BLK_U4; i += THREADS) zbase[i] = z;

    __syncthreads();

    // ---- Phase 2: scatter-max into own rows ----
    if ((unsigned)id < (unsigned)VOCAB) {  // defensive: never fault
        const unsigned u   = __float_as_uint(w);
        const unsigned val = ((u + 0x7FFFu + ((u >> 16) & 1u)) >> 16) << 16;
        if (val != 0u) {
            const int row = blk * ROWS_PER_BLOCK + (t >> 8);  // t/SEQ in {0,1}
            atomicMax(out + ((long long)row * VOCAB + id), val);
        }
    }
}

extern "C" void kernel_launch(void* const* d_in, const int* in_sizes, int n_in,
                              void* d_out, int out_size, void* d_ws, size_t ws_size,
                              hipStream_t stream) {
    const int*   ids = (const int*)d_in[0];
    const float* ws  = (const float*)d_in[1];

    TargetEncoder_532575944857_kernel
        <<<BATCH / ROWS_PER_BLOCK, THREADS, 0, stream>>>(
            ids, ws, (unsigned int*)d_out);
}